// Round 13
// baseline (242.640 us; speedup 1.0000x reference)
//
#include <hip/hip_runtime.h>
#include <math.h>

#define HOP 441
#define NMEL 80

typedef __attribute__((ext_vector_type(8))) short bf16x8;
typedef __attribute__((ext_vector_type(4))) float f32x4;

__device__ __forceinline__ float2 cmulf(float2 a, float2 b) {
    return make_float2(a.x * b.x - a.y * b.y, a.x * b.y + a.y * b.x);
}
__device__ __forceinline__ float2 cadd(float2 a, float2 b) {
    return make_float2(a.x + b.x, a.y + b.y);
}
__device__ __forceinline__ float2 csub(float2 a, float2 b) {
    return make_float2(a.x - b.x, a.y - b.y);
}
__device__ __forceinline__ float2 shx2(float2 v, int m) {
    return make_float2(__shfl_xor(v.x, m, 64), __shfl_xor(v.y, m, 64));
}
__device__ __forceinline__ float2 shidx2(float2 v, int src) {
    return make_float2(__shfl(v.x, src, 64), __shfl(v.y, src, 64));
}
__device__ __forceinline__ int brev6f(int v) {
    return ((v & 1) << 5) | ((v & 2) << 3) | ((v & 4) << 1) |
           ((v & 8) >> 1) | ((v & 16) >> 3) | ((v & 32) >> 5);
}
__device__ __forceinline__ int brevn(int v, int bits) {
    int r = 0;
    for (int i = 0; i < bits; ++i) r |= ((v >> i) & 1) << (bits - 1 - i);
    return r;
}
__device__ __forceinline__ float2 w32t(int m) {
    constexpr float C[16] = {1.0f, 0.980785280f, 0.923879533f, 0.831469612f,
                             0.707106781f, 0.555570233f, 0.382683432f, 0.195090322f,
                             0.0f, -0.195090322f, -0.382683432f, -0.555570233f,
                             -0.707106781f, -0.831469612f, -0.923879533f, -0.980785280f};
    constexpr float S[16] = {0.0f, 0.195090322f, 0.382683432f, 0.555570233f,
                             0.707106781f, 0.831469612f, 0.923879533f, 0.980785280f,
                             1.0f, 0.980785280f, 0.923879533f, 0.831469612f,
                             0.707106781f, 0.555570233f, 0.382683432f, 0.195090322f};
    return make_float2(C[m], -S[m]);
}
__device__ __forceinline__ unsigned short bf16t(float v) {
    return (unsigned short)(__float_as_uint(v) >> 16);
}

// ================== FFT body (R10 structure: one wave = one frame, straight-line;
// z[] must stay register-resident — no frame loops around this body) ==================
template<int FLEN, int KPAD>
__device__ __forceinline__ void fft_body(const float* __restrict__ x, const float* __restrict__ win,
                                         unsigned short* __restrict__ pows_g, int T, int n0,
                                         int bx, int b, uint4* __restrict__ powsU) {
    constexpr int N    = FLEN / 2;
    constexpr int R    = N / 64;
    constexpr int LOGR = (R == 32) ? 5 : ((R == 16) ? 4 : 3);
    constexpr int R2_  = R / 2;
    constexpr int HALF = FLEN / 2;
    constexpr int NOCT = KPAD / 8;
    constexpr float PI = 3.14159265358979f;

    unsigned short* ldsw = (unsigned short*)powsU + (threadIdx.x >> 6) * KPAD;

    const int tid = threadIdx.x;
    const int sub = tid >> 6;                       // wave = frame
    const int p   = tid & 63;
    const int s   = brev6f(p);
    const int t0  = bx * 4;

    // zero the padded tail rows (N+1 .. KPAD-1)
    if (p < KPAD - (N + 1)) ldsw[N + 1 + p] = 0;

    float2 W32s, W16s, W8s, W4s, W2s, wl, Pp, ub;
    float sg32, sg16, sg8, sg4, sg2, sg1;
    {
        float s_, c_;
        __sincosf(-PI * (float)(p & 31) / 32.0f, &s_, &c_);
        W32s = (p & 32) ? make_float2(c_, s_) : make_float2(1.0f, 0.0f);
        sg32 = (p & 32) ? -1.0f : 1.0f;
        __sincosf(-PI * (float)(p & 15) / 16.0f, &s_, &c_);
        W16s = (p & 16) ? make_float2(c_, s_) : make_float2(1.0f, 0.0f);
        sg16 = (p & 16) ? -1.0f : 1.0f;
        __sincosf(-PI * (float)(p & 7) / 8.0f, &s_, &c_);
        W8s  = (p & 8) ? make_float2(c_, s_) : make_float2(1.0f, 0.0f);
        sg8  = (p & 8) ? -1.0f : 1.0f;
        __sincosf(-PI * (float)(p & 3) / 4.0f, &s_, &c_);
        W4s  = (p & 4) ? make_float2(c_, s_) : make_float2(1.0f, 0.0f);
        sg4  = (p & 4) ? -1.0f : 1.0f;
        __sincosf(-PI * (float)(p & 1) / 2.0f, &s_, &c_);
        W2s  = (p & 2) ? make_float2(c_, s_) : make_float2(1.0f, 0.0f);
        sg2  = (p & 2) ? -1.0f : 1.0f;
        sg1  = (p & 1) ? -1.0f : 1.0f;
        __sincosf(-2.0f * PI * (float)p / (float)N, &s_, &c_); wl = make_float2(c_, s_);
        __sincosf(PI * (float)s / 64.0f, &s_, &c_);             Pp = make_float2(c_, s_);
        __sincosf(PI / (float)N, &s_, &c_);                     ub = make_float2(c_, s_);
    }
    const int mpart = brev6f((64 - s) & 63);

    const float* xb = x + (size_t)b * (size_t)T;
    const int Tp = T + HALF;

    const int t = t0 + sub;
    const bool valid = (t < n0);
    const int start = HOP * t;
    int pad = start + FLEN - Tp; if (pad < 0) pad = 0;
    const int base = start - pad - HALF;

    float2 z[R];
    if (pad == 0 && base >= 0 && valid) {
        const float*  xp = xb + base + 2 * p;
        const float2* wp = ((const float2*)win) + p;
        #pragma unroll
        for (int j = 0; j < R; ++j) {
            const int q = brevn(j, LOGR);
            const float2 wv = wp[64 * q];
            z[j] = make_float2(xp[128 * q] * wv.x, xp[128 * q + 1] * wv.y);
        }
    } else {
        #pragma unroll
        for (int j = 0; j < R; ++j) {
            const int q  = brevn(j, LOGR);
            const int i  = 64 * q + p;
            const int j0 = 2 * i;
            const float2 wv = ((const float2*)win)[i];
            const int xi0 = base + j0;
            float v0 = (valid && j0 >= pad     && xi0 >= 0)     ? xb[xi0] * wv.x     : 0.0f;
            float v1 = (valid && j0 + 1 >= pad && xi0 + 1 >= 0) ? xb[xi0 + 1] * wv.y : 0.0f;
            z[j] = make_float2(v0, v1);
        }
    }

    // lane-local R-point DIT FFT
    #pragma unroll
    for (int h = 1; h < R; h <<= 1) {
        #pragma unroll
        for (int base2 = 0; base2 < R; base2 += 2 * h) {
            #pragma unroll
            for (int i = 0; i < h; ++i) {
                const float2 W  = w32t((16 * i) / h);
                const float2 tt = cmulf(W, z[base2 + i + h]);
                const float2 aa = z[base2 + i];
                z[base2 + i]     = cadd(aa, tt);
                z[base2 + i + h] = csub(aa, tt);
            }
        }
    }

    // per-lane twiddle w_N^(p*r), 4 independent chains
    {
        const float2 w2c = cmulf(wl, wl);
        const float2 w3c = cmulf(w2c, wl);
        const float2 w4c = cmulf(w2c, w2c);
        z[1] = cmulf(z[1], wl);
        z[2] = cmulf(z[2], w2c);
        z[3] = cmulf(z[3], w3c);
        float2 a0 = w4c, a1 = cmulf(wl, w4c), a2 = cmulf(w2c, w4c), a3 = cmulf(w3c, w4c);
        #pragma unroll
        for (int g = 4; g < R; g += 4) {
            z[g]     = cmulf(z[g],     a0);
            z[g + 1] = cmulf(z[g + 1], a1);
            z[g + 2] = cmulf(z[g + 2], a2);
            z[g + 3] = cmulf(z[g + 3], a3);
            if (g + 4 < R) {
                a0 = cmulf(a0, w4c); a1 = cmulf(a1, w4c);
                a2 = cmulf(a2, w4c); a3 = cmulf(a3, w4c);
            }
        }
    }

    // cross-lane 64-point DIF FFT
#define XSTAGE(MASK, W, SG) { \
        _Pragma("unroll") \
        for (int j = 0; j < R; ++j) { \
            const float2 xq = shx2(z[j], MASK); \
            const float2 d  = make_float2(fmaf(SG, z[j].x, xq.x), \
                                          fmaf(SG, z[j].y, xq.y)); \
            z[j] = cmulf(d, W); \
        } }
    XSTAGE(32, W32s, sg32)
    XSTAGE(16, W16s, sg16)
    XSTAGE(8,  W8s,  sg8)
    XSTAGE(4,  W4s,  sg4)
    XSTAGE(2,  W2s,  sg2)
    #pragma unroll
    for (int j = 0; j < R; ++j) {
        const float2 xq = shx2(z[j], 1);
        z[j] = make_float2(fmaf(sg1, z[j].x, xq.x), fmaf(sg1, z[j].y, xq.y));
    }
#undef XSTAGE

    // PAIR rfft unpack -> swizzled LDS rows (0.5-scalings folded into 0.25*pw; exact)
#define SWZK(KK) (((KK) & ~(R - 1)) | (((KK) & (R - 1)) ^ (((KK) >> LOGR) & (R - 1))))
#define PAIRE(RR, ZK, ZN, CW, SW) { \
        const float Er = (ZK).x + (ZN).x, Ei = (ZK).y - (ZN).y; \
        const float Or = (ZK).y + (ZN).y, Oi = -((ZK).x - (ZN).x); \
        const float Tr = (CW) * Or + (SW) * Oi; \
        const float Ti = (CW) * Oi - (SW) * Or; \
        const float Xr0 = Er + Tr, Xi0 = Ei + Ti; \
        const float Xr1 = Er - Tr, Xi1 = Ei - Ti; \
        const float pw0 = 0.25f * (Xr0 * Xr0 + Xi0 * Xi0); \
        const float pw1 = 0.25f * (Xr1 * Xr1 + Xi1 * Xi1); \
        const int k0b = R * s + (RR); \
        const int km  = N - k0b; \
        ldsw[SWZK(k0b)] = bf16t(pw0); \
        ldsw[SWZK(km)]  = bf16t(pw1); }

    {
        const float2 ub2 = cmulf(ub, ub);
        const float2 ub4 = cmulf(ub2, ub2);
        float2 c0 = Pp, c1 = cmulf(Pp, ub), c2 = cmulf(Pp, ub2), c3 = cmulf(c1, ub2);
        {
            const float2 Zn = shidx2(z[0], mpart);
            PAIRE(0, z[0], Zn, c0.x, c0.y)
        }
        { const float2 Zn = shx2(z[R - 1], 63); PAIRE(1, z[1], Zn, c1.x, c1.y) }
        { const float2 Zn = shx2(z[R - 2], 63); PAIRE(2, z[2], Zn, c2.x, c2.y) }
        { const float2 Zn = shx2(z[R - 3], 63); PAIRE(3, z[3], Zn, c3.x, c3.y) }
        #pragma unroll
        for (int g = 4; g <= R2_; g += 4) {
            c0 = cmulf(c0, ub4); c1 = cmulf(c1, ub4);
            c2 = cmulf(c2, ub4); c3 = cmulf(c3, ub4);
            { const float2 Zn = shx2(z[R - g], 63); PAIRE(g, z[g], Zn, c0.x, c0.y) }
            if (g + 1 <= R2_) { const float2 Zn = shx2(z[R - g - 1], 63); PAIRE(g + 1, z[g + 1], Zn, c1.x, c1.y) }
            if (g + 2 <= R2_) { const float2 Zn = shx2(z[R - g - 2], 63); PAIRE(g + 2, z[g + 2], Zn, c2.x, c2.y) }
            if (g + 3 <= R2_) { const float2 Zn = shx2(z[R - g - 3], 63); PAIRE(g + 3, z[g + 3], Zn, c3.x, c3.y) }
        }
    }
#undef PAIRE
#undef SWZK

    // coalesced transpose-out: raw (still-swizzled) rows -> global A rows
    if (valid) {
        const uint4* src = powsU + sub * (KPAD / 8);
        uint4* dst = (uint4*)(pows_g + (size_t)((size_t)b * n0 + t) * KPAD);
        #pragma unroll
        for (int w = 0; w < (NOCT + 63) / 64; ++w) {
            const int oct = p + 64 * w;
            if (oct < NOCT) dst[oct] = src[oct];
        }
    }
}

// ============ mel convert body (bakes the involution into melT) ============
template<int KPAD, int LOGR, int R, int K>
__device__ __forceinline__ void melcvt_one(const float* __restrict__ mel,
                                           unsigned short* __restrict__ melT, int idx) {
    const int n = idx / KPAD, pos = idx - n * KPAD;
    const int k = (pos & ~(R - 1)) | ((pos & (R - 1)) ^ ((pos >> LOGR) & (R - 1)));
    unsigned short v = 0;
    if (k < K) {
        const unsigned u = __float_as_uint(mel[(size_t)k * NMEL + n]);
        v = (unsigned short)((u + 0x7FFF + ((u >> 16) & 1)) >> 16);   // RNE
    }
    melT[(size_t)n * KPAD + pos] = v;
}

// ============ mel GEMM body via MFMA: one wave = 16 frames x 16 mels, full K ============
// N-split 5x for grid parallelism (96 -> 480 blocks); each output written once.
template<int KPAD, int SZI>
__device__ __forceinline__ void gemm_body(const unsigned short* __restrict__ powsA,
                                          const unsigned short* __restrict__ melT,
                                          float* __restrict__ out, int Mvalid,
                                          int ftile, int nt) {
    constexpr int NCH = KPAD / 32;

    const int tid = threadIdx.x;
    const int w   = tid >> 6;
    const int l   = tid & 63;
    const int frame0 = ftile * 64 + w * 16;

    const unsigned short* Ap = powsA + (size_t)(frame0 + (l & 15)) * KPAD + (l >> 4) * 8;
    const unsigned short* Bp = melT + (size_t)(nt * 16 + (l & 15)) * KPAD + (l >> 4) * 8;

    f32x4 acc = {0.0f, 0.0f, 0.0f, 0.0f};

    #pragma unroll 4
    for (int c = 0; c < NCH; ++c) {
        const bf16x8 a  = *(const bf16x8*)(Ap + c * 32);
        const bf16x8 bb = *(const bf16x8*)(Bp + c * 32);
        acc = __builtin_amdgcn_mfma_f32_16x16x32_bf16(a, bb, acc, 0, 0, 0);
    }

    #pragma unroll
    for (int q = 0; q < 4; ++q) {
        const int row = (l >> 4) * 4 + q;
        const int col = nt * 16 + (l & 15);
        const int frame = frame0 + row;
        if (frame < Mvalid)
            out[((size_t)frame * NMEL + col) * 3 + SZI] = logf(acc[q] + 1e-16f);
    }
}

// ================== K1: all three FFTs + mel-convert, one launch ==================
__global__ __launch_bounds__(256, 4)
void k_ffts(const float* __restrict__ x,
            const float* __restrict__ w1, const float* __restrict__ w2, const float* __restrict__ w4,
            const float* __restrict__ m1, const float* __restrict__ m2, const float* __restrict__ m4,
            unsigned short* __restrict__ p1, unsigned short* __restrict__ p2, unsigned short* __restrict__ p4,
            unsigned short* __restrict__ m1t, unsigned short* __restrict__ m2t, unsigned short* __restrict__ m4t,
            int T, int n0, int gx) {
    __shared__ uint4 sh[4 * 2080 / 8];              // max branch LDS (16640 B)
    int bid = blockIdx.x;
    const int nf = gx * 8;
    if (bid < nf) { fft_body<4096, 2080>(x, w4, p4, T, n0, bid % gx, bid / gx, sh); return; }
    bid -= nf;
    if (bid < nf) { fft_body<2048, 1056>(x, w2, p2, T, n0, bid % gx, bid / gx, sh); return; }
    bid -= nf;
    if (bid < nf) { fft_body<1024,  544>(x, w1, p1, T, n0, bid % gx, bid / gx, sh); return; }
    bid -= nf;
    int idx = bid * 256 + (int)threadIdx.x;
    constexpr int S1 = NMEL * 544, S2 = NMEL * 1056, S4 = NMEL * 2080;
    if (idx < S1) { melcvt_one< 544, 3,  8,  513>(m1, m1t, idx); return; }
    idx -= S1;
    if (idx < S2) { melcvt_one<1056, 4, 16, 1025>(m2, m2t, idx); return; }
    idx -= S2;
    if (idx < S4) melcvt_one<2080, 5, 32, 2049>(m4, m4t, idx);
}

// ================== K2: all three mel GEMMs (N-split 5x), one launch ==================
__global__ __launch_bounds__(256)
void k_gemms(const unsigned short* __restrict__ p1, const unsigned short* __restrict__ p2,
             const unsigned short* __restrict__ p4,
             const unsigned short* __restrict__ m1t, const unsigned short* __restrict__ m2t,
             const unsigned short* __restrict__ m4t,
             float* __restrict__ out, int Mvalid, int ngemm) {
    int bid = blockIdx.x;
    const int n5 = ngemm * 5;
    if (bid < n5) { gemm_body<2080, 2>(p4, m4t, out, Mvalid, bid / 5, bid % 5); return; }
    bid -= n5;
    if (bid < n5) { gemm_body<1056, 1>(p2, m2t, out, Mvalid, bid / 5, bid % 5); return; }
    bid -= n5;
    gemm_body< 544, 0>(p1, m1t, out, Mvalid, bid / 5, bid % 5);
}

// ================== FALLBACK (exact R7 kernel, known-passing) ==================
template<int FLEN, int SZI>
__global__ __launch_bounds__(512, 4)
void spect_kernel(const float* __restrict__ x, const float* __restrict__ win,
                  const float* __restrict__ mel, float* __restrict__ out,
                  int T, int n0) {
    constexpr int N    = FLEN / 2;
    constexpr int R    = N / 64;
    constexpr int LOGR = (R == 32) ? 5 : ((R == 16) ? 4 : 3);
    constexpr int R2_  = R / 2;
    constexpr int K    = N + 1;
    constexpr int KP   = N + 8;
    constexpr int HALF = FLEN / 2;
    constexpr int NT   = 512;
    constexpr int FPB  = 8;
    constexpr float PI = 3.14159265358979f;

    __shared__ uint4 pows4[KP];
    __shared__ float res[FPB * NMEL];
    unsigned short* pows = (unsigned short*)pows4;

    const int tid = threadIdx.x;
    const int sub = tid >> 6;
    const int p   = tid & 63;
    const int s   = brev6f(p);
    const int b   = blockIdx.y;
    const int t0  = blockIdx.x * FPB;

    for (int i = tid; i < FPB * NMEL; i += NT) res[i] = 0.0f;

    float2 W32s, W16s, W8s, W4s, W2s, wl, Pp, ub;
    float sg32, sg16, sg8, sg4, sg2, sg1;
    {
        float s_, c_;
        __sincosf(-PI * (float)(p & 31) / 32.0f, &s_, &c_);
        W32s = (p & 32) ? make_float2(c_, s_) : make_float2(1.0f, 0.0f);
        sg32 = (p & 32) ? -1.0f : 1.0f;
        __sincosf(-PI * (float)(p & 15) / 16.0f, &s_, &c_);
        W16s = (p & 16) ? make_float2(c_, s_) : make_float2(1.0f, 0.0f);
        sg16 = (p & 16) ? -1.0f : 1.0f;
        __sincosf(-PI * (float)(p & 7) / 8.0f, &s_, &c_);
        W8s  = (p & 8) ? make_float2(c_, s_) : make_float2(1.0f, 0.0f);
        sg8  = (p & 8) ? -1.0f : 1.0f;
        __sincosf(-PI * (float)(p & 3) / 4.0f, &s_, &c_);
        W4s  = (p & 4) ? make_float2(c_, s_) : make_float2(1.0f, 0.0f);
        sg4  = (p & 4) ? -1.0f : 1.0f;
        __sincosf(-PI * (float)(p & 1) / 2.0f, &s_, &c_);
        W2s  = (p & 2) ? make_float2(c_, s_) : make_float2(1.0f, 0.0f);
        sg2  = (p & 2) ? -1.0f : 1.0f;
        sg1  = (p & 1) ? -1.0f : 1.0f;
        __sincosf(-2.0f * PI * (float)p / (float)N, &s_, &c_); wl = make_float2(c_, s_);
        __sincosf(PI * (float)s / 64.0f, &s_, &c_);             Pp = make_float2(c_, s_);
        __sincosf(PI / (float)N, &s_, &c_);                     ub = make_float2(c_, s_);
    }
    const int mpart = brev6f((64 - s) & 63);

    const float* xb = x + (size_t)b * (size_t)T;
    const int Tp = T + HALF;

    const int t = t0 + sub;
    const bool valid = (t < n0);
    const int start = HOP * t;
    int pad = start + FLEN - Tp; if (pad < 0) pad = 0;
    const int base = start - pad - HALF;

    float2 z[R];
    if (pad == 0 && base >= 0 && valid) {
        const float*  xp = xb + base + 2 * p;
        const float2* wp = ((const float2*)win) + p;
        #pragma unroll
        for (int j = 0; j < R; ++j) {
            const int q = brevn(j, LOGR);
            const float2 wv = wp[64 * q];
            z[j] = make_float2(xp[128 * q] * wv.x, xp[128 * q + 1] * wv.y);
        }
    } else {
        #pragma unroll
        for (int j = 0; j < R; ++j) {
            const int q  = brevn(j, LOGR);
            const int i  = 64 * q + p;
            const int j0 = 2 * i;
            const float2 wv = ((const float2*)win)[i];
            const int xi0 = base + j0;
            float v0 = (valid && j0 >= pad     && xi0 >= 0)     ? xb[xi0] * wv.x     : 0.0f;
            float v1 = (valid && j0 + 1 >= pad && xi0 + 1 >= 0) ? xb[xi0 + 1] * wv.y : 0.0f;
            z[j] = make_float2(v0, v1);
        }
    }

    #pragma unroll
    for (int h = 1; h < R; h <<= 1) {
        #pragma unroll
        for (int base2 = 0; base2 < R; base2 += 2 * h) {
            #pragma unroll
            for (int i = 0; i < h; ++i) {
                const float2 W  = w32t((16 * i) / h);
                const float2 tt = cmulf(W, z[base2 + i + h]);
                const float2 aa = z[base2 + i];
                z[base2 + i]     = cadd(aa, tt);
                z[base2 + i + h] = csub(aa, tt);
            }
        }
    }

    {
        const float2 w2c = cmulf(wl, wl);
        const float2 w3c = cmulf(w2c, wl);
        const float2 w4c = cmulf(w2c, w2c);
        z[1] = cmulf(z[1], wl);
        z[2] = cmulf(z[2], w2c);
        z[3] = cmulf(z[3], w3c);
        float2 a0 = w4c, a1 = cmulf(wl, w4c), a2 = cmulf(w2c, w4c), a3 = cmulf(w3c, w4c);
        #pragma unroll
        for (int g = 4; g < R; g += 4) {
            z[g]     = cmulf(z[g],     a0);
            z[g + 1] = cmulf(z[g + 1], a1);
            z[g + 2] = cmulf(z[g + 2], a2);
            z[g + 3] = cmulf(z[g + 3], a3);
            if (g + 4 < R) {
                a0 = cmulf(a0, w4c); a1 = cmulf(a1, w4c);
                a2 = cmulf(a2, w4c); a3 = cmulf(a3, w4c);
            }
        }
    }

#define XSTAGE(MASK, W, SG) { \
        _Pragma("unroll") \
        for (int j = 0; j < R; ++j) { \
            const float2 xq = shx2(z[j], MASK); \
            const float2 d  = make_float2(fmaf(SG, z[j].x, xq.x), \
                                          fmaf(SG, z[j].y, xq.y)); \
            z[j] = cmulf(d, W); \
        } }
    XSTAGE(32, W32s, sg32)
    XSTAGE(16, W16s, sg16)
    XSTAGE(8,  W8s,  sg8)
    XSTAGE(4,  W4s,  sg4)
    XSTAGE(2,  W2s,  sg2)
    #pragma unroll
    for (int j = 0; j < R; ++j) {
        const float2 xq = shx2(z[j], 1);
        z[j] = make_float2(fmaf(sg1, z[j].x, xq.x), fmaf(sg1, z[j].y, xq.y));
    }
#undef XSTAGE

#define PAIRE(RR, ZK, ZN, CW, SW) { \
        const float Er = 0.5f * ((ZK).x + (ZN).x), Ei = 0.5f * ((ZK).y - (ZN).y); \
        const float Or = 0.5f * ((ZK).y + (ZN).y), Oi = -0.5f * ((ZK).x - (ZN).x); \
        const float Tr = (CW) * Or + (SW) * Oi; \
        const float Ti = (CW) * Oi - (SW) * Or; \
        const float Xr0 = Er + Tr, Xi0 = Ei + Ti; \
        const float Xr1 = Er - Tr, Xi1 = Ei - Ti; \
        const float pw0 = Xr0 * Xr0 + Xi0 * Xi0; \
        const float pw1 = Xr1 * Xr1 + Xi1 * Xi1; \
        const int k0b  = R * s + (RR); \
        const int km   = N - k0b; \
        const int row0 = (k0b & ~(R - 1)) | ((k0b & (R - 1)) ^ (s & 7)); \
        const int row1 = (km  & ~(R - 1)) | ((km  & (R - 1)) ^ ((km >> LOGR) & 7)); \
        pows[row0 * 8 + sub] = bf16t(pw0); \
        pows[row1 * 8 + sub] = bf16t(pw1); }

    {
        const float2 ub2 = cmulf(ub, ub);
        const float2 ub4 = cmulf(ub2, ub2);
        float2 c0 = Pp, c1 = cmulf(Pp, ub), c2 = cmulf(Pp, ub2), c3 = cmulf(c1, ub2);
        {
            const float2 Zn = shidx2(z[0], mpart);
            PAIRE(0, z[0], Zn, c0.x, c0.y)
        }
        { const float2 Zn = shx2(z[R - 1], 63); PAIRE(1, z[1], Zn, c1.x, c1.y) }
        { const float2 Zn = shx2(z[R - 2], 63); PAIRE(2, z[2], Zn, c2.x, c2.y) }
        { const float2 Zn = shx2(z[R - 3], 63); PAIRE(3, z[3], Zn, c3.x, c3.y) }
        #pragma unroll
        for (int g = 4; g <= R2_; g += 4) {
            c0 = cmulf(c0, ub4); c1 = cmulf(c1, ub4);
            c2 = cmulf(c2, ub4); c3 = cmulf(c3, ub4);
            { const float2 Zn = shx2(z[R - g], 63); PAIRE(g, z[g], Zn, c0.x, c0.y) }
            if (g + 1 <= R2_) { const float2 Zn = shx2(z[R - g - 1], 63); PAIRE(g + 1, z[g + 1], Zn, c1.x, c1.y) }
            if (g + 2 <= R2_) { const float2 Zn = shx2(z[R - g - 2], 63); PAIRE(g + 2, z[g + 2], Zn, c2.x, c2.y) }
            if (g + 3 <= R2_) { const float2 Zn = shx2(z[R - g - 3], 63); PAIRE(g + 3, z[g + 3], Zn, c3.x, c3.y) }
        }
    }
#undef PAIRE

    __syncthreads();

    constexpr int NCH = 25;
    constexpr int CH  = (K + NCH - 1) / NCH;
    if (tid < NCH * 20) {
        const int g  = tid % 20;
        const int cc = tid / 20;
        const int k0 = cc * CH;
        const int k1 = (k0 + CH < K) ? (k0 + CH) : K;
        float acc[FPB][4];
        #pragma unroll
        for (int f2 = 0; f2 < FPB; ++f2) {
            acc[f2][0] = 0.f; acc[f2][1] = 0.f; acc[f2][2] = 0.f; acc[f2][3] = 0.f;
        }
        #pragma unroll 4
        for (int k = k0; k < k1; ++k) {
            const int kmel = (k & ~(R - 1)) | ((k & (R - 1)) ^ ((k >> LOGR) & 7));
            const float4 mr = *(const float4*)(mel + (size_t)kmel * NMEL + 4 * g);
            const uint4 pv = pows4[k];
#define ACC2(W32, BASE) { \
            const float p0 = __uint_as_float((W32) << 16); \
            const float p1 = __uint_as_float((W32) & 0xFFFF0000u); \
            acc[BASE][0] += p0 * mr.x; acc[BASE][1] += p0 * mr.y; \
            acc[BASE][2] += p0 * mr.z; acc[BASE][3] += p0 * mr.w; \
            acc[(BASE)+1][0] += p1 * mr.x; acc[(BASE)+1][1] += p1 * mr.y; \
            acc[(BASE)+1][2] += p1 * mr.z; acc[(BASE)+1][3] += p1 * mr.w; }
            ACC2(pv.x, 0) ACC2(pv.y, 2) ACC2(pv.z, 4) ACC2(pv.w, 6)
#undef ACC2
        }
        #pragma unroll
        for (int f2 = 0; f2 < FPB; ++f2) {
            #pragma unroll
            for (int mi = 0; mi < 4; ++mi) {
                atomicAdd(&res[f2 * NMEL + 4 * g + mi], acc[f2][mi]);
            }
        }
    }
    __syncthreads();

    const size_t outbase = (size_t)b * (size_t)n0 * NMEL * 3;
    for (int i = tid; i < FPB * NMEL; i += NT) {
        const int f2 = i / NMEL;
        const int m  = i % NMEL;
        const int tt = t0 + f2;
        if (tt < n0) {
            out[outbase + ((size_t)tt * NMEL + m) * 3 + SZI] = logf(res[i] + 1e-16f);
        }
    }
}

extern "C" void kernel_launch(void* const* d_in, const int* in_sizes, int n_in,
                              void* d_out, int out_size, void* d_ws, size_t ws_size,
                              hipStream_t stream) {
    const float* x  = (const float*)d_in[0];
    const float* w1 = (const float*)d_in[1];
    const float* m1 = (const float*)d_in[2];
    const float* w2 = (const float*)d_in[3];
    const float* m2 = (const float*)d_in[4];
    const float* w4 = (const float*)d_in[5];
    const float* m4 = (const float*)d_in[6];
    float* out = (float*)d_out;

    const int B  = 8;
    const int T  = in_sizes[0] / B;
    const int n0 = (T + 512 + 440) / 441;   // ceil((T + 1024/2) / 441)

    const size_t M    = (size_t)B * (size_t)n0;
    const size_t Mpad = (M + 63) & ~(size_t)63;          // 64-frame GEMM tiles
    const size_t KP1 = 544, KP2 = 1056, KP4 = 2080;
    const size_t need = (Mpad + NMEL) * (KP1 + KP2 + KP4) * 2;

    if (ws_size >= need) {
        unsigned short* p1  = (unsigned short*)d_ws;
        unsigned short* p2  = p1 + Mpad * KP1;
        unsigned short* p4  = p2 + Mpad * KP2;
        unsigned short* m1t = p4 + Mpad * KP4;
        unsigned short* m2t = m1t + NMEL * KP1;
        unsigned short* m4t = m2t + NMEL * KP2;

        const int gx  = (n0 + 3) / 4;
        const int nf  = gx * 8;
        const int cvt = (NMEL * (544 + 1056 + 2080) + 255) / 256;
        const int ngemm = (int)(Mpad / 64);

        k_ffts<<<3 * nf + cvt, 256, 0, stream>>>(x, w1, w2, w4, m1, m2, m4,
                                                 p1, p2, p4, m1t, m2t, m4t, T, n0, gx);
        k_gemms<<<15 * ngemm, 256, 0, stream>>>(p1, p2, p4, m1t, m2t, m4t,
                                                out, (int)M, ngemm);
    } else {
        const int gxf = (n0 + 7) / 8;
        spect_kernel<1024, 0><<<dim3(gxf, B), 512, 0, stream>>>(x, w1, m1, out, T, n0);
        spect_kernel<2048, 1><<<dim3(gxf, B), 512, 0, stream>>>(x, w2, m2, out, T, n0);
        spect_kernel<4096, 2><<<dim3(gxf, B), 512, 0, stream>>>(x, w4, m4, out, T, n0);
    }
}

// Round 14
// 209.932 us; speedup vs baseline: 1.1558x; 1.1558x over previous
//
#include <hip/hip_runtime.h>
#include <math.h>

#define HOP 441
#define NMEL 80

typedef __attribute__((ext_vector_type(8))) short bf16x8;
typedef __attribute__((ext_vector_type(4))) float f32x4;

__device__ __forceinline__ float2 cmulf(float2 a, float2 b) {
    return make_float2(a.x * b.x - a.y * b.y, a.x * b.y + a.y * b.x);
}
__device__ __forceinline__ float2 cadd(float2 a, float2 b) {
    return make_float2(a.x + b.x, a.y + b.y);
}
__device__ __forceinline__ float2 csub(float2 a, float2 b) {
    return make_float2(a.x - b.x, a.y - b.y);
}
__device__ __forceinline__ float2 shx2(float2 v, int m) {
    return make_float2(__shfl_xor(v.x, m, 64), __shfl_xor(v.y, m, 64));
}
__device__ __forceinline__ float2 shidx2(float2 v, int src) {
    return make_float2(__shfl(v.x, src, 64), __shfl(v.y, src, 64));
}
__device__ __forceinline__ int brev6f(int v) {
    return ((v & 1) << 5) | ((v & 2) << 3) | ((v & 4) << 1) |
           ((v & 8) >> 1) | ((v & 16) >> 3) | ((v & 32) >> 5);
}
__device__ __forceinline__ int brevn(int v, int bits) {
    int r = 0;
    for (int i = 0; i < bits; ++i) r |= ((v >> i) & 1) << (bits - 1 - i);
    return r;
}
__device__ __forceinline__ float2 w32t(int m) {
    constexpr float C[16] = {1.0f, 0.980785280f, 0.923879533f, 0.831469612f,
                             0.707106781f, 0.555570233f, 0.382683432f, 0.195090322f,
                             0.0f, -0.195090322f, -0.382683432f, -0.555570233f,
                             -0.707106781f, -0.831469612f, -0.923879533f, -0.980785280f};
    constexpr float S[16] = {0.0f, 0.195090322f, 0.382683432f, 0.555570233f,
                             0.707106781f, 0.831469612f, 0.923879533f, 0.980785280f,
                             1.0f, 0.980785280f, 0.923879533f, 0.831469612f,
                             0.707106781f, 0.555570233f, 0.382683432f, 0.195090322f};
    return make_float2(C[m], -S[m]);
}
__device__ __forceinline__ unsigned short bf16t(float v) {
    return (unsigned short)(__float_as_uint(v) >> 16);
}

// ================== FFT body (R10 structure: one wave = one frame, straight-line;
// z[] must stay register-resident — no frame loops around this body) ==================
template<int FLEN, int KPAD>
__device__ __forceinline__ void fft_body(const float* __restrict__ x, const float* __restrict__ win,
                                         unsigned short* __restrict__ pows_g, int T, int n0,
                                         int bx, int b, uint4* __restrict__ powsU) {
    constexpr int N    = FLEN / 2;
    constexpr int R    = N / 64;
    constexpr int LOGR = (R == 32) ? 5 : ((R == 16) ? 4 : 3);
    constexpr int R2_  = R / 2;
    constexpr int HALF = FLEN / 2;
    constexpr int NOCT = KPAD / 8;
    constexpr float PI = 3.14159265358979f;

    unsigned short* ldsw = (unsigned short*)powsU + (threadIdx.x >> 6) * KPAD;

    const int tid = threadIdx.x;
    const int sub = tid >> 6;                       // wave = frame
    const int p   = tid & 63;
    const int s   = brev6f(p);
    const int t0  = bx * 4;

    // zero the padded tail rows (N+1 .. KPAD-1)
    if (p < KPAD - (N + 1)) ldsw[N + 1 + p] = 0;

    float2 W32s, W16s, W8s, W4s, W2s, wl, Pp, ub;
    float sg32, sg16, sg8, sg4, sg2, sg1;
    {
        float s_, c_;
        __sincosf(-PI * (float)(p & 31) / 32.0f, &s_, &c_);
        W32s = (p & 32) ? make_float2(c_, s_) : make_float2(1.0f, 0.0f);
        sg32 = (p & 32) ? -1.0f : 1.0f;
        __sincosf(-PI * (float)(p & 15) / 16.0f, &s_, &c_);
        W16s = (p & 16) ? make_float2(c_, s_) : make_float2(1.0f, 0.0f);
        sg16 = (p & 16) ? -1.0f : 1.0f;
        __sincosf(-PI * (float)(p & 7) / 8.0f, &s_, &c_);
        W8s  = (p & 8) ? make_float2(c_, s_) : make_float2(1.0f, 0.0f);
        sg8  = (p & 8) ? -1.0f : 1.0f;
        __sincosf(-PI * (float)(p & 3) / 4.0f, &s_, &c_);
        W4s  = (p & 4) ? make_float2(c_, s_) : make_float2(1.0f, 0.0f);
        sg4  = (p & 4) ? -1.0f : 1.0f;
        __sincosf(-PI * (float)(p & 1) / 2.0f, &s_, &c_);
        W2s  = (p & 2) ? make_float2(c_, s_) : make_float2(1.0f, 0.0f);
        sg2  = (p & 2) ? -1.0f : 1.0f;
        sg1  = (p & 1) ? -1.0f : 1.0f;
        __sincosf(-2.0f * PI * (float)p / (float)N, &s_, &c_); wl = make_float2(c_, s_);
        __sincosf(PI * (float)s / 64.0f, &s_, &c_);             Pp = make_float2(c_, s_);
        __sincosf(PI / (float)N, &s_, &c_);                     ub = make_float2(c_, s_);
    }
    const int mpart = brev6f((64 - s) & 63);

    const float* xb = x + (size_t)b * (size_t)T;
    const int Tp = T + HALF;

    const int t = t0 + sub;
    const bool valid = (t < n0);
    const int start = HOP * t;
    int pad = start + FLEN - Tp; if (pad < 0) pad = 0;
    const int base = start - pad - HALF;

    float2 z[R];
    if (pad == 0 && base >= 0 && valid) {
        const float*  xp = xb + base + 2 * p;
        const float2* wp = ((const float2*)win) + p;
        #pragma unroll
        for (int j = 0; j < R; ++j) {
            const int q = brevn(j, LOGR);
            const float2 wv = wp[64 * q];
            z[j] = make_float2(xp[128 * q] * wv.x, xp[128 * q + 1] * wv.y);
        }
    } else {
        #pragma unroll
        for (int j = 0; j < R; ++j) {
            const int q  = brevn(j, LOGR);
            const int i  = 64 * q + p;
            const int j0 = 2 * i;
            const float2 wv = ((const float2*)win)[i];
            const int xi0 = base + j0;
            float v0 = (valid && j0 >= pad     && xi0 >= 0)     ? xb[xi0] * wv.x     : 0.0f;
            float v1 = (valid && j0 + 1 >= pad && xi0 + 1 >= 0) ? xb[xi0 + 1] * wv.y : 0.0f;
            z[j] = make_float2(v0, v1);
        }
    }

    // lane-local R-point DIT FFT
    #pragma unroll
    for (int h = 1; h < R; h <<= 1) {
        #pragma unroll
        for (int base2 = 0; base2 < R; base2 += 2 * h) {
            #pragma unroll
            for (int i = 0; i < h; ++i) {
                const float2 W  = w32t((16 * i) / h);
                const float2 tt = cmulf(W, z[base2 + i + h]);
                const float2 aa = z[base2 + i];
                z[base2 + i]     = cadd(aa, tt);
                z[base2 + i + h] = csub(aa, tt);
            }
        }
    }

    // per-lane twiddle w_N^(p*r), 4 independent chains
    {
        const float2 w2c = cmulf(wl, wl);
        const float2 w3c = cmulf(w2c, wl);
        const float2 w4c = cmulf(w2c, w2c);
        z[1] = cmulf(z[1], wl);
        z[2] = cmulf(z[2], w2c);
        z[3] = cmulf(z[3], w3c);
        float2 a0 = w4c, a1 = cmulf(wl, w4c), a2 = cmulf(w2c, w4c), a3 = cmulf(w3c, w4c);
        #pragma unroll
        for (int g = 4; g < R; g += 4) {
            z[g]     = cmulf(z[g],     a0);
            z[g + 1] = cmulf(z[g + 1], a1);
            z[g + 2] = cmulf(z[g + 2], a2);
            z[g + 3] = cmulf(z[g + 3], a3);
            if (g + 4 < R) {
                a0 = cmulf(a0, w4c); a1 = cmulf(a1, w4c);
                a2 = cmulf(a2, w4c); a3 = cmulf(a3, w4c);
            }
        }
    }

    // cross-lane 64-point DIF FFT
#define XSTAGE(MASK, W, SG) { \
        _Pragma("unroll") \
        for (int j = 0; j < R; ++j) { \
            const float2 xq = shx2(z[j], MASK); \
            const float2 d  = make_float2(fmaf(SG, z[j].x, xq.x), \
                                          fmaf(SG, z[j].y, xq.y)); \
            z[j] = cmulf(d, W); \
        } }
    XSTAGE(32, W32s, sg32)
    XSTAGE(16, W16s, sg16)
    XSTAGE(8,  W8s,  sg8)
    XSTAGE(4,  W4s,  sg4)
    XSTAGE(2,  W2s,  sg2)
    #pragma unroll
    for (int j = 0; j < R; ++j) {
        const float2 xq = shx2(z[j], 1);
        z[j] = make_float2(fmaf(sg1, z[j].x, xq.x), fmaf(sg1, z[j].y, xq.y));
    }
#undef XSTAGE

    // PAIR rfft unpack -> swizzled LDS rows (0.5-scalings folded into 0.25*pw; exact)
#define SWZK(KK) (((KK) & ~(R - 1)) | (((KK) & (R - 1)) ^ (((KK) >> LOGR) & (R - 1))))
#define PAIRE(RR, ZK, ZN, CW, SW) { \
        const float Er = (ZK).x + (ZN).x, Ei = (ZK).y - (ZN).y; \
        const float Or = (ZK).y + (ZN).y, Oi = -((ZK).x - (ZN).x); \
        const float Tr = (CW) * Or + (SW) * Oi; \
        const float Ti = (CW) * Oi - (SW) * Or; \
        const float Xr0 = Er + Tr, Xi0 = Ei + Ti; \
        const float Xr1 = Er - Tr, Xi1 = Ei - Ti; \
        const float pw0 = 0.25f * (Xr0 * Xr0 + Xi0 * Xi0); \
        const float pw1 = 0.25f * (Xr1 * Xr1 + Xi1 * Xi1); \
        const int k0b = R * s + (RR); \
        const int km  = N - k0b; \
        ldsw[SWZK(k0b)] = bf16t(pw0); \
        ldsw[SWZK(km)]  = bf16t(pw1); }

    {
        const float2 ub2 = cmulf(ub, ub);
        const float2 ub4 = cmulf(ub2, ub2);
        float2 c0 = Pp, c1 = cmulf(Pp, ub), c2 = cmulf(Pp, ub2), c3 = cmulf(c1, ub2);
        {
            const float2 Zn = shidx2(z[0], mpart);
            PAIRE(0, z[0], Zn, c0.x, c0.y)
        }
        { const float2 Zn = shx2(z[R - 1], 63); PAIRE(1, z[1], Zn, c1.x, c1.y) }
        { const float2 Zn = shx2(z[R - 2], 63); PAIRE(2, z[2], Zn, c2.x, c2.y) }
        { const float2 Zn = shx2(z[R - 3], 63); PAIRE(3, z[3], Zn, c3.x, c3.y) }
        #pragma unroll
        for (int g = 4; g <= R2_; g += 4) {
            c0 = cmulf(c0, ub4); c1 = cmulf(c1, ub4);
            c2 = cmulf(c2, ub4); c3 = cmulf(c3, ub4);
            { const float2 Zn = shx2(z[R - g], 63); PAIRE(g, z[g], Zn, c0.x, c0.y) }
            if (g + 1 <= R2_) { const float2 Zn = shx2(z[R - g - 1], 63); PAIRE(g + 1, z[g + 1], Zn, c1.x, c1.y) }
            if (g + 2 <= R2_) { const float2 Zn = shx2(z[R - g - 2], 63); PAIRE(g + 2, z[g + 2], Zn, c2.x, c2.y) }
            if (g + 3 <= R2_) { const float2 Zn = shx2(z[R - g - 3], 63); PAIRE(g + 3, z[g + 3], Zn, c3.x, c3.y) }
        }
    }
#undef PAIRE
#undef SWZK

    // coalesced transpose-out: raw (still-swizzled) rows -> global A rows
    if (valid) {
        const uint4* src = powsU + sub * (KPAD / 8);
        uint4* dst = (uint4*)(pows_g + (size_t)((size_t)b * n0 + t) * KPAD);
        #pragma unroll
        for (int w = 0; w < (NOCT + 63) / 64; ++w) {
            const int oct = p + 64 * w;
            if (oct < NOCT) dst[oct] = src[oct];
        }
    }
}

// ============ mel convert body (bakes the involution into melT) ============
template<int KPAD, int LOGR, int R, int K>
__device__ __forceinline__ void melcvt_one(const float* __restrict__ mel,
                                           unsigned short* __restrict__ melT, int idx) {
    const int n = idx / KPAD, pos = idx - n * KPAD;
    const int k = (pos & ~(R - 1)) | ((pos & (R - 1)) ^ ((pos >> LOGR) & (R - 1)));
    unsigned short v = 0;
    if (k < K) {
        const unsigned u = __float_as_uint(mel[(size_t)k * NMEL + n]);
        v = (unsigned short)((u + 0x7FFF + ((u >> 16) & 1)) >> 16);   // RNE
    }
    melT[(size_t)n * KPAD + pos] = v;
}

// ============ mel GEMM body (R8-proven): one block = one 16-frame tile,
// 4 waves split K with acc[5] ILP each, LDS reduce, wave 0 log+store ============
template<int KPAD, int SZI>
__device__ __forceinline__ void gemm_body(const unsigned short* __restrict__ powsA,
                                          const unsigned short* __restrict__ melT,
                                          float* __restrict__ out, int Mvalid, int mt,
                                          float* __restrict__ red) {
    constexpr int NCH = KPAD / 32;

    const int tid = threadIdx.x;
    const int w   = tid >> 6;
    const int l   = tid & 63;

    const unsigned short* Ap = powsA + (size_t)(mt * 16 + (l & 15)) * KPAD + (l >> 4) * 8;
    const unsigned short* Bp = melT + (size_t)(l & 15) * KPAD + (l >> 4) * 8;

    f32x4 acc[5];
    const f32x4 z4 = {0.0f, 0.0f, 0.0f, 0.0f};
    #pragma unroll
    for (int nt = 0; nt < 5; ++nt) acc[nt] = z4;

    const int cpw = (NCH + 3) >> 2;
    const int c0 = w * cpw;
    const int c1 = (c0 + cpw < NCH) ? (c0 + cpw) : NCH;
    for (int c = c0; c < c1; ++c) {
        const bf16x8 a = *(const bf16x8*)(Ap + c * 32);
        #pragma unroll
        for (int nt = 0; nt < 5; ++nt) {
            const bf16x8 bb = *(const bf16x8*)(Bp + (size_t)nt * 16 * KPAD + c * 32);
            acc[nt] = __builtin_amdgcn_mfma_f32_16x16x32_bf16(a, bb, acc[nt], 0, 0, 0);
        }
    }

    if (w > 0) {
        #pragma unroll
        for (int nt = 0; nt < 5; ++nt) {
            #pragma unroll
            for (int q = 0; q < 4; ++q) {
                const int row = (l >> 4) * 4 + q;
                const int col = nt * 16 + (l & 15);
                red[(w - 1) * 16 * NMEL + row * NMEL + col] = acc[nt][q];
            }
        }
    }
    __syncthreads();
    if (w == 0) {
        #pragma unroll
        for (int nt = 0; nt < 5; ++nt) {
            #pragma unroll
            for (int q = 0; q < 4; ++q) {
                const int row = (l >> 4) * 4 + q;
                const int col = nt * 16 + (l & 15);
                float v = acc[nt][q] + red[0 * 16 * NMEL + row * NMEL + col]
                        + red[1 * 16 * NMEL + row * NMEL + col]
                        + red[2 * 16 * NMEL + row * NMEL + col];
                const int frame = mt * 16 + row;
                if (frame < Mvalid)
                    out[((size_t)frame * NMEL + col) * 3 + SZI] = logf(v + 1e-16f);
            }
        }
    }
}

// ================== K1: all three FFTs + mel-convert, one launch ==================
__global__ __launch_bounds__(256, 4)
void k_ffts(const float* __restrict__ x,
            const float* __restrict__ w1, const float* __restrict__ w2, const float* __restrict__ w4,
            const float* __restrict__ m1, const float* __restrict__ m2, const float* __restrict__ m4,
            unsigned short* __restrict__ p1, unsigned short* __restrict__ p2, unsigned short* __restrict__ p4,
            unsigned short* __restrict__ m1t, unsigned short* __restrict__ m2t, unsigned short* __restrict__ m4t,
            int T, int n0, int gx) {
    __shared__ uint4 sh[4 * 2080 / 8];              // max branch LDS (16640 B)
    int bid = blockIdx.x;
    const int nf = gx * 8;
    if (bid < nf) { fft_body<4096, 2080>(x, w4, p4, T, n0, bid % gx, bid / gx, sh); return; }
    bid -= nf;
    if (bid < nf) { fft_body<2048, 1056>(x, w2, p2, T, n0, bid % gx, bid / gx, sh); return; }
    bid -= nf;
    if (bid < nf) { fft_body<1024,  544>(x, w1, p1, T, n0, bid % gx, bid / gx, sh); return; }
    bid -= nf;
    int idx = bid * 256 + (int)threadIdx.x;
    constexpr int S1 = NMEL * 544, S2 = NMEL * 1056, S4 = NMEL * 2080;
    if (idx < S1) { melcvt_one< 544, 3,  8,  513>(m1, m1t, idx); return; }
    idx -= S1;
    if (idx < S2) { melcvt_one<1056, 4, 16, 1025>(m2, m2t, idx); return; }
    idx -= S2;
    if (idx < S4) melcvt_one<2080, 5, 32, 2049>(m4, m4t, idx);
}

// ================== K2: all three mel GEMMs (K-split 4x per tile), one launch ==================
__global__ __launch_bounds__(256)
void k_gemms(const unsigned short* __restrict__ p1, const unsigned short* __restrict__ p2,
             const unsigned short* __restrict__ p4,
             const unsigned short* __restrict__ m1t, const unsigned short* __restrict__ m2t,
             const unsigned short* __restrict__ m4t,
             float* __restrict__ out, int Mvalid, int ntile) {
    __shared__ float red[3 * 16 * NMEL];
    int bid = blockIdx.x;
    if (bid < ntile) { gemm_body<2080, 2>(p4, m4t, out, Mvalid, bid, red); return; }
    bid -= ntile;
    if (bid < ntile) { gemm_body<1056, 1>(p2, m2t, out, Mvalid, bid, red); return; }
    bid -= ntile;
    gemm_body< 544, 0>(p1, m1t, out, Mvalid, bid, red);
}

// ================== FALLBACK (exact R7 kernel, known-passing) ==================
template<int FLEN, int SZI>
__global__ __launch_bounds__(512, 4)
void spect_kernel(const float* __restrict__ x, const float* __restrict__ win,
                  const float* __restrict__ mel, float* __restrict__ out,
                  int T, int n0) {
    constexpr int N    = FLEN / 2;
    constexpr int R    = N / 64;
    constexpr int LOGR = (R == 32) ? 5 : ((R == 16) ? 4 : 3);
    constexpr int R2_  = R / 2;
    constexpr int K    = N + 1;
    constexpr int KP   = N + 8;
    constexpr int HALF = FLEN / 2;
    constexpr int NT   = 512;
    constexpr int FPB  = 8;
    constexpr float PI = 3.14159265358979f;

    __shared__ uint4 pows4[KP];
    __shared__ float res[FPB * NMEL];
    unsigned short* pows = (unsigned short*)pows4;

    const int tid = threadIdx.x;
    const int sub = tid >> 6;
    const int p   = tid & 63;
    const int s   = brev6f(p);
    const int b   = blockIdx.y;
    const int t0  = blockIdx.x * FPB;

    for (int i = tid; i < FPB * NMEL; i += NT) res[i] = 0.0f;

    float2 W32s, W16s, W8s, W4s, W2s, wl, Pp, ub;
    float sg32, sg16, sg8, sg4, sg2, sg1;
    {
        float s_, c_;
        __sincosf(-PI * (float)(p & 31) / 32.0f, &s_, &c_);
        W32s = (p & 32) ? make_float2(c_, s_) : make_float2(1.0f, 0.0f);
        sg32 = (p & 32) ? -1.0f : 1.0f;
        __sincosf(-PI * (float)(p & 15) / 16.0f, &s_, &c_);
        W16s = (p & 16) ? make_float2(c_, s_) : make_float2(1.0f, 0.0f);
        sg16 = (p & 16) ? -1.0f : 1.0f;
        __sincosf(-PI * (float)(p & 7) / 8.0f, &s_, &c_);
        W8s  = (p & 8) ? make_float2(c_, s_) : make_float2(1.0f, 0.0f);
        sg8  = (p & 8) ? -1.0f : 1.0f;
        __sincosf(-PI * (float)(p & 3) / 4.0f, &s_, &c_);
        W4s  = (p & 4) ? make_float2(c_, s_) : make_float2(1.0f, 0.0f);
        sg4  = (p & 4) ? -1.0f : 1.0f;
        __sincosf(-PI * (float)(p & 1) / 2.0f, &s_, &c_);
        W2s  = (p & 2) ? make_float2(c_, s_) : make_float2(1.0f, 0.0f);
        sg2  = (p & 2) ? -1.0f : 1.0f;
        sg1  = (p & 1) ? -1.0f : 1.0f;
        __sincosf(-2.0f * PI * (float)p / (float)N, &s_, &c_); wl = make_float2(c_, s_);
        __sincosf(PI * (float)s / 64.0f, &s_, &c_);             Pp = make_float2(c_, s_);
        __sincosf(PI / (float)N, &s_, &c_);                     ub = make_float2(c_, s_);
    }
    const int mpart = brev6f((64 - s) & 63);

    const float* xb = x + (size_t)b * (size_t)T;
    const int Tp = T + HALF;

    const int t = t0 + sub;
    const bool valid = (t < n0);
    const int start = HOP * t;
    int pad = start + FLEN - Tp; if (pad < 0) pad = 0;
    const int base = start - pad - HALF;

    float2 z[R];
    if (pad == 0 && base >= 0 && valid) {
        const float*  xp = xb + base + 2 * p;
        const float2* wp = ((const float2*)win) + p;
        #pragma unroll
        for (int j = 0; j < R; ++j) {
            const int q = brevn(j, LOGR);
            const float2 wv = wp[64 * q];
            z[j] = make_float2(xp[128 * q] * wv.x, xp[128 * q + 1] * wv.y);
        }
    } else {
        #pragma unroll
        for (int j = 0; j < R; ++j) {
            const int q  = brevn(j, LOGR);
            const int i  = 64 * q + p;
            const int j0 = 2 * i;
            const float2 wv = ((const float2*)win)[i];
            const int xi0 = base + j0;
            float v0 = (valid && j0 >= pad     && xi0 >= 0)     ? xb[xi0] * wv.x     : 0.0f;
            float v1 = (valid && j0 + 1 >= pad && xi0 + 1 >= 0) ? xb[xi0 + 1] * wv.y : 0.0f;
            z[j] = make_float2(v0, v1);
        }
    }

    #pragma unroll
    for (int h = 1; h < R; h <<= 1) {
        #pragma unroll
        for (int base2 = 0; base2 < R; base2 += 2 * h) {
            #pragma unroll
            for (int i = 0; i < h; ++i) {
                const float2 W  = w32t((16 * i) / h);
                const float2 tt = cmulf(W, z[base2 + i + h]);
                const float2 aa = z[base2 + i];
                z[base2 + i]     = cadd(aa, tt);
                z[base2 + i + h] = csub(aa, tt);
            }
        }
    }

    {
        const float2 w2c = cmulf(wl, wl);
        const float2 w3c = cmulf(w2c, wl);
        const float2 w4c = cmulf(w2c, w2c);
        z[1] = cmulf(z[1], wl);
        z[2] = cmulf(z[2], w2c);
        z[3] = cmulf(z[3], w3c);
        float2 a0 = w4c, a1 = cmulf(wl, w4c), a2 = cmulf(w2c, w4c), a3 = cmulf(w3c, w4c);
        #pragma unroll
        for (int g = 4; g < R; g += 4) {
            z[g]     = cmulf(z[g],     a0);
            z[g + 1] = cmulf(z[g + 1], a1);
            z[g + 2] = cmulf(z[g + 2], a2);
            z[g + 3] = cmulf(z[g + 3], a3);
            if (g + 4 < R) {
                a0 = cmulf(a0, w4c); a1 = cmulf(a1, w4c);
                a2 = cmulf(a2, w4c); a3 = cmulf(a3, w4c);
            }
        }
    }

#define XSTAGE(MASK, W, SG) { \
        _Pragma("unroll") \
        for (int j = 0; j < R; ++j) { \
            const float2 xq = shx2(z[j], MASK); \
            const float2 d  = make_float2(fmaf(SG, z[j].x, xq.x), \
                                          fmaf(SG, z[j].y, xq.y)); \
            z[j] = cmulf(d, W); \
        } }
    XSTAGE(32, W32s, sg32)
    XSTAGE(16, W16s, sg16)
    XSTAGE(8,  W8s,  sg8)
    XSTAGE(4,  W4s,  sg4)
    XSTAGE(2,  W2s,  sg2)
    #pragma unroll
    for (int j = 0; j < R; ++j) {
        const float2 xq = shx2(z[j], 1);
        z[j] = make_float2(fmaf(sg1, z[j].x, xq.x), fmaf(sg1, z[j].y, xq.y));
    }
#undef XSTAGE

#define PAIRE(RR, ZK, ZN, CW, SW) { \
        const float Er = 0.5f * ((ZK).x + (ZN).x), Ei = 0.5f * ((ZK).y - (ZN).y); \
        const float Or = 0.5f * ((ZK).y + (ZN).y), Oi = -0.5f * ((ZK).x - (ZN).x); \
        const float Tr = (CW) * Or + (SW) * Oi; \
        const float Ti = (CW) * Oi - (SW) * Or; \
        const float Xr0 = Er + Tr, Xi0 = Ei + Ti; \
        const float Xr1 = Er - Tr, Xi1 = Ei - Ti; \
        const float pw0 = Xr0 * Xr0 + Xi0 * Xi0; \
        const float pw1 = Xr1 * Xr1 + Xi1 * Xi1; \
        const int k0b  = R * s + (RR); \
        const int km   = N - k0b; \
        const int row0 = (k0b & ~(R - 1)) | ((k0b & (R - 1)) ^ (s & 7)); \
        const int row1 = (km  & ~(R - 1)) | ((km  & (R - 1)) ^ ((km >> LOGR) & 7)); \
        pows[row0 * 8 + sub] = bf16t(pw0); \
        pows[row1 * 8 + sub] = bf16t(pw1); }

    {
        const float2 ub2 = cmulf(ub, ub);
        const float2 ub4 = cmulf(ub2, ub2);
        float2 c0 = Pp, c1 = cmulf(Pp, ub), c2 = cmulf(Pp, ub2), c3 = cmulf(c1, ub2);
        {
            const float2 Zn = shidx2(z[0], mpart);
            PAIRE(0, z[0], Zn, c0.x, c0.y)
        }
        { const float2 Zn = shx2(z[R - 1], 63); PAIRE(1, z[1], Zn, c1.x, c1.y) }
        { const float2 Zn = shx2(z[R - 2], 63); PAIRE(2, z[2], Zn, c2.x, c2.y) }
        { const float2 Zn = shx2(z[R - 3], 63); PAIRE(3, z[3], Zn, c3.x, c3.y) }
        #pragma unroll
        for (int g = 4; g <= R2_; g += 4) {
            c0 = cmulf(c0, ub4); c1 = cmulf(c1, ub4);
            c2 = cmulf(c2, ub4); c3 = cmulf(c3, ub4);
            { const float2 Zn = shx2(z[R - g], 63); PAIRE(g, z[g], Zn, c0.x, c0.y) }
            if (g + 1 <= R2_) { const float2 Zn = shx2(z[R - g - 1], 63); PAIRE(g + 1, z[g + 1], Zn, c1.x, c1.y) }
            if (g + 2 <= R2_) { const float2 Zn = shx2(z[R - g - 2], 63); PAIRE(g + 2, z[g + 2], Zn, c2.x, c2.y) }
            if (g + 3 <= R2_) { const float2 Zn = shx2(z[R - g - 3], 63); PAIRE(g + 3, z[g + 3], Zn, c3.x, c3.y) }
        }
    }
#undef PAIRE

    __syncthreads();

    constexpr int NCH = 25;
    constexpr int CH  = (K + NCH - 1) / NCH;
    if (tid < NCH * 20) {
        const int g  = tid % 20;
        const int cc = tid / 20;
        const int k0 = cc * CH;
        const int k1 = (k0 + CH < K) ? (k0 + CH) : K;
        float acc[FPB][4];
        #pragma unroll
        for (int f2 = 0; f2 < FPB; ++f2) {
            acc[f2][0] = 0.f; acc[f2][1] = 0.f; acc[f2][2] = 0.f; acc[f2][3] = 0.f;
        }
        #pragma unroll 4
        for (int k = k0; k < k1; ++k) {
            const int kmel = (k & ~(R - 1)) | ((k & (R - 1)) ^ ((k >> LOGR) & 7));
            const float4 mr = *(const float4*)(mel + (size_t)kmel * NMEL + 4 * g);
            const uint4 pv = pows4[k];
#define ACC2(W32, BASE) { \
            const float p0 = __uint_as_float((W32) << 16); \
            const float p1 = __uint_as_float((W32) & 0xFFFF0000u); \
            acc[BASE][0] += p0 * mr.x; acc[BASE][1] += p0 * mr.y; \
            acc[BASE][2] += p0 * mr.z; acc[BASE][3] += p0 * mr.w; \
            acc[(BASE)+1][0] += p1 * mr.x; acc[(BASE)+1][1] += p1 * mr.y; \
            acc[(BASE)+1][2] += p1 * mr.z; acc[(BASE)+1][3] += p1 * mr.w; }
            ACC2(pv.x, 0) ACC2(pv.y, 2) ACC2(pv.z, 4) ACC2(pv.w, 6)
#undef ACC2
        }
        #pragma unroll
        for (int f2 = 0; f2 < FPB; ++f2) {
            #pragma unroll
            for (int mi = 0; mi < 4; ++mi) {
                atomicAdd(&res[f2 * NMEL + 4 * g + mi], acc[f2][mi]);
            }
        }
    }
    __syncthreads();

    const size_t outbase = (size_t)b * (size_t)n0 * NMEL * 3;
    for (int i = tid; i < FPB * NMEL; i += NT) {
        const int f2 = i / NMEL;
        const int m  = i % NMEL;
        const int tt = t0 + f2;
        if (tt < n0) {
            out[outbase + ((size_t)tt * NMEL + m) * 3 + SZI] = logf(res[i] + 1e-16f);
        }
    }
}

extern "C" void kernel_launch(void* const* d_in, const int* in_sizes, int n_in,
                              void* d_out, int out_size, void* d_ws, size_t ws_size,
                              hipStream_t stream) {
    const float* x  = (const float*)d_in[0];
    const float* w1 = (const float*)d_in[1];
    const float* m1 = (const float*)d_in[2];
    const float* w2 = (const float*)d_in[3];
    const float* m2 = (const float*)d_in[4];
    const float* w4 = (const float*)d_in[5];
    const float* m4 = (const float*)d_in[6];
    float* out = (float*)d_out;

    const int B  = 8;
    const int T  = in_sizes[0] / B;
    const int n0 = (T + 512 + 440) / 441;   // ceil((T + 1024/2) / 441)

    const size_t M    = (size_t)B * (size_t)n0;
    const size_t Mpad = (M + 63) & ~(size_t)63;          // 64-frame-aligned A rows
    const size_t KP1 = 544, KP2 = 1056, KP4 = 2080;
    const size_t need = (Mpad + NMEL) * (KP1 + KP2 + KP4) * 2;

    if (ws_size >= need) {
        unsigned short* p1  = (unsigned short*)d_ws;
        unsigned short* p2  = p1 + Mpad * KP1;
        unsigned short* p4  = p2 + Mpad * KP2;
        unsigned short* m1t = p4 + Mpad * KP4;
        unsigned short* m2t = m1t + NMEL * KP1;
        unsigned short* m4t = m2t + NMEL * KP2;

        const int gx  = (n0 + 3) / 4;
        const int nf  = gx * 8;
        const int cvt = (NMEL * (544 + 1056 + 2080) + 255) / 256;
        const int ntile = (int)(Mpad / 16);              // 16-frame tiles per size

        k_ffts<<<3 * nf + cvt, 256, 0, stream>>>(x, w1, w2, w4, m1, m2, m4,
                                                 p1, p2, p4, m1t, m2t, m4t, T, n0, gx);
        k_gemms<<<3 * ntile, 256, 0, stream>>>(p1, p2, p4, m1t, m2t, m4t,
                                               out, (int)M, ntile);
    } else {
        const int gxf = (n0 + 7) / 8;
        spect_kernel<1024, 0><<<dim3(gxf, B), 512, 0, stream>>>(x, w1, m1, out, T, n0);
        spect_kernel<2048, 1><<<dim3(gxf, B), 512, 0, stream>>>(x, w2, m2, out, T, n0);
        spect_kernel<4096, 2><<<dim3(gxf, B), 512, 0, stream>>>(x, w4, m4, out, T, n0);
    }
}

// Round 15
// 201.838 us; speedup vs baseline: 1.2022x; 1.0401x over previous
//
#include <hip/hip_runtime.h>
#include <math.h>

#define HOP 441
#define NMEL 80

typedef __attribute__((ext_vector_type(8))) short bf16x8;
typedef __attribute__((ext_vector_type(4))) float f32x4;

__device__ __forceinline__ float2 cmulf(float2 a, float2 b) {
    return make_float2(a.x * b.x - a.y * b.y, a.x * b.y + a.y * b.x);
}
__device__ __forceinline__ float2 cadd(float2 a, float2 b) {
    return make_float2(a.x + b.x, a.y + b.y);
}
__device__ __forceinline__ float2 csub(float2 a, float2 b) {
    return make_float2(a.x - b.x, a.y - b.y);
}
__device__ __forceinline__ float2 shx2(float2 v, int m) {
    return make_float2(__shfl_xor(v.x, m, 64), __shfl_xor(v.y, m, 64));
}
__device__ __forceinline__ float2 shidx2(float2 v, int src) {
    return make_float2(__shfl(v.x, src, 64), __shfl(v.y, src, 64));
}
__device__ __forceinline__ int brev6f(int v) {
    return ((v & 1) << 5) | ((v & 2) << 3) | ((v & 4) << 1) |
           ((v & 8) >> 1) | ((v & 16) >> 3) | ((v & 32) >> 5);
}
__device__ __forceinline__ int brevn(int v, int bits) {
    int r = 0;
    for (int i = 0; i < bits; ++i) r |= ((v >> i) & 1) << (bits - 1 - i);
    return r;
}
__device__ __forceinline__ float2 w32t(int m) {
    constexpr float C[16] = {1.0f, 0.980785280f, 0.923879533f, 0.831469612f,
                             0.707106781f, 0.555570233f, 0.382683432f, 0.195090322f,
                             0.0f, -0.195090322f, -0.382683432f, -0.555570233f,
                             -0.707106781f, -0.831469612f, -0.923879533f, -0.980785280f};
    constexpr float S[16] = {0.0f, 0.195090322f, 0.382683432f, 0.555570233f,
                             0.707106781f, 0.831469612f, 0.923879533f, 0.980785280f,
                             1.0f, 0.980785280f, 0.923879533f, 0.831469612f,
                             0.707106781f, 0.555570233f, 0.382683432f, 0.195090322f};
    return make_float2(C[m], -S[m]);
}
__device__ __forceinline__ unsigned short bf16t(float v) {
    return (unsigned short)(__float_as_uint(v) >> 16);
}

// ================== FFT body (R10 structure: one wave = one frame, straight-line;
// z[] must stay register-resident — no frame loops around this body) ==================
template<int FLEN, int KPAD>
__device__ __forceinline__ void fft_body(const float* __restrict__ x, const float* __restrict__ win,
                                         unsigned short* __restrict__ pows_g, int T, int n0,
                                         int bx, int b, uint4* __restrict__ powsU) {
    constexpr int N    = FLEN / 2;
    constexpr int R    = N / 64;
    constexpr int LOGR = (R == 32) ? 5 : ((R == 16) ? 4 : 3);
    constexpr int R2_  = R / 2;
    constexpr int HALF = FLEN / 2;
    constexpr int NOCT = KPAD / 8;
    constexpr float PI = 3.14159265358979f;

    unsigned short* ldsw = (unsigned short*)powsU + (threadIdx.x >> 6) * KPAD;

    const int tid = threadIdx.x;
    const int sub = tid >> 6;                       // wave = frame
    const int p   = tid & 63;
    const int s   = brev6f(p);
    const int t0  = bx * 4;

    // zero the padded tail rows (N+1 .. KPAD-1)
    if (p < KPAD - (N + 1)) ldsw[N + 1 + p] = 0;

    float2 W32s, W16s, W8s, W4s, W2s, wl, Pp, ub;
    float sg32, sg16, sg8, sg4, sg2, sg1;
    {
        float s_, c_;
        __sincosf(-PI * (float)(p & 31) / 32.0f, &s_, &c_);
        W32s = (p & 32) ? make_float2(c_, s_) : make_float2(1.0f, 0.0f);
        sg32 = (p & 32) ? -1.0f : 1.0f;
        __sincosf(-PI * (float)(p & 15) / 16.0f, &s_, &c_);
        W16s = (p & 16) ? make_float2(c_, s_) : make_float2(1.0f, 0.0f);
        sg16 = (p & 16) ? -1.0f : 1.0f;
        __sincosf(-PI * (float)(p & 7) / 8.0f, &s_, &c_);
        W8s  = (p & 8) ? make_float2(c_, s_) : make_float2(1.0f, 0.0f);
        sg8  = (p & 8) ? -1.0f : 1.0f;
        __sincosf(-PI * (float)(p & 3) / 4.0f, &s_, &c_);
        W4s  = (p & 4) ? make_float2(c_, s_) : make_float2(1.0f, 0.0f);
        sg4  = (p & 4) ? -1.0f : 1.0f;
        __sincosf(-PI * (float)(p & 1) / 2.0f, &s_, &c_);
        W2s  = (p & 2) ? make_float2(c_, s_) : make_float2(1.0f, 0.0f);
        sg2  = (p & 2) ? -1.0f : 1.0f;
        sg1  = (p & 1) ? -1.0f : 1.0f;
        __sincosf(-2.0f * PI * (float)p / (float)N, &s_, &c_); wl = make_float2(c_, s_);
        __sincosf(PI * (float)s / 64.0f, &s_, &c_);             Pp = make_float2(c_, s_);
        __sincosf(PI / (float)N, &s_, &c_);                     ub = make_float2(c_, s_);
    }
    const int mpart = brev6f((64 - s) & 63);

    const float* xb = x + (size_t)b * (size_t)T;
    const int Tp = T + HALF;

    const int t = t0 + sub;
    const bool valid = (t < n0);
    const int start = HOP * t;
    int pad = start + FLEN - Tp; if (pad < 0) pad = 0;
    const int base = start - pad - HALF;

    float2 z[R];
    if (pad == 0 && base >= 0 && valid) {
        const float*  xp = xb + base + 2 * p;
        const float2* wp = ((const float2*)win) + p;
        #pragma unroll
        for (int j = 0; j < R; ++j) {
            const int q = brevn(j, LOGR);
            const float2 wv = wp[64 * q];
            z[j] = make_float2(xp[128 * q] * wv.x, xp[128 * q + 1] * wv.y);
        }
    } else {
        #pragma unroll
        for (int j = 0; j < R; ++j) {
            const int q  = brevn(j, LOGR);
            const int i  = 64 * q + p;
            const int j0 = 2 * i;
            const float2 wv = ((const float2*)win)[i];
            const int xi0 = base + j0;
            float v0 = (valid && j0 >= pad     && xi0 >= 0)     ? xb[xi0] * wv.x     : 0.0f;
            float v1 = (valid && j0 + 1 >= pad && xi0 + 1 >= 0) ? xb[xi0 + 1] * wv.y : 0.0f;
            z[j] = make_float2(v0, v1);
        }
    }

    // lane-local R-point DIT FFT
    #pragma unroll
    for (int h = 1; h < R; h <<= 1) {
        #pragma unroll
        for (int base2 = 0; base2 < R; base2 += 2 * h) {
            #pragma unroll
            for (int i = 0; i < h; ++i) {
                const float2 W  = w32t((16 * i) / h);
                const float2 tt = cmulf(W, z[base2 + i + h]);
                const float2 aa = z[base2 + i];
                z[base2 + i]     = cadd(aa, tt);
                z[base2 + i + h] = csub(aa, tt);
            }
        }
    }

    // per-lane twiddle w_N^(p*r), 4 independent chains
    {
        const float2 w2c = cmulf(wl, wl);
        const float2 w3c = cmulf(w2c, wl);
        const float2 w4c = cmulf(w2c, w2c);
        z[1] = cmulf(z[1], wl);
        z[2] = cmulf(z[2], w2c);
        z[3] = cmulf(z[3], w3c);
        float2 a0 = w4c, a1 = cmulf(wl, w4c), a2 = cmulf(w2c, w4c), a3 = cmulf(w3c, w4c);
        #pragma unroll
        for (int g = 4; g < R; g += 4) {
            z[g]     = cmulf(z[g],     a0);
            z[g + 1] = cmulf(z[g + 1], a1);
            z[g + 2] = cmulf(z[g + 2], a2);
            z[g + 3] = cmulf(z[g + 3], a3);
            if (g + 4 < R) {
                a0 = cmulf(a0, w4c); a1 = cmulf(a1, w4c);
                a2 = cmulf(a2, w4c); a3 = cmulf(a3, w4c);
            }
        }
    }

    // cross-lane 64-point DIF FFT
#define XSTAGE(MASK, W, SG) { \
        _Pragma("unroll") \
        for (int j = 0; j < R; ++j) { \
            const float2 xq = shx2(z[j], MASK); \
            const float2 d  = make_float2(fmaf(SG, z[j].x, xq.x), \
                                          fmaf(SG, z[j].y, xq.y)); \
            z[j] = cmulf(d, W); \
        } }
    XSTAGE(32, W32s, sg32)
    XSTAGE(16, W16s, sg16)
    XSTAGE(8,  W8s,  sg8)
    XSTAGE(4,  W4s,  sg4)
    XSTAGE(2,  W2s,  sg2)
    #pragma unroll
    for (int j = 0; j < R; ++j) {
        const float2 xq = shx2(z[j], 1);
        z[j] = make_float2(fmaf(sg1, z[j].x, xq.x), fmaf(sg1, z[j].y, xq.y));
    }
#undef XSTAGE

    // PAIR rfft unpack -> swizzled LDS rows (0.5-scalings folded into 0.25*pw; exact)
#define SWZK(KK) (((KK) & ~(R - 1)) | (((KK) & (R - 1)) ^ (((KK) >> LOGR) & (R - 1))))
#define PAIRE(RR, ZK, ZN, CW, SW) { \
        const float Er = (ZK).x + (ZN).x, Ei = (ZK).y - (ZN).y; \
        const float Or = (ZK).y + (ZN).y, Oi = -((ZK).x - (ZN).x); \
        const float Tr = (CW) * Or + (SW) * Oi; \
        const float Ti = (CW) * Oi - (SW) * Or; \
        const float Xr0 = Er + Tr, Xi0 = Ei + Ti; \
        const float Xr1 = Er - Tr, Xi1 = Ei - Ti; \
        const float pw0 = 0.25f * (Xr0 * Xr0 + Xi0 * Xi0); \
        const float pw1 = 0.25f * (Xr1 * Xr1 + Xi1 * Xi1); \
        const int k0b = R * s + (RR); \
        const int km  = N - k0b; \
        ldsw[SWZK(k0b)] = bf16t(pw0); \
        ldsw[SWZK(km)]  = bf16t(pw1); }

    {
        const float2 ub2 = cmulf(ub, ub);
        const float2 ub4 = cmulf(ub2, ub2);
        float2 c0 = Pp, c1 = cmulf(Pp, ub), c2 = cmulf(Pp, ub2), c3 = cmulf(c1, ub2);
        {
            const float2 Zn = shidx2(z[0], mpart);
            PAIRE(0, z[0], Zn, c0.x, c0.y)
        }
        { const float2 Zn = shx2(z[R - 1], 63); PAIRE(1, z[1], Zn, c1.x, c1.y) }
        { const float2 Zn = shx2(z[R - 2], 63); PAIRE(2, z[2], Zn, c2.x, c2.y) }
        { const float2 Zn = shx2(z[R - 3], 63); PAIRE(3, z[3], Zn, c3.x, c3.y) }
        #pragma unroll
        for (int g = 4; g <= R2_; g += 4) {
            c0 = cmulf(c0, ub4); c1 = cmulf(c1, ub4);
            c2 = cmulf(c2, ub4); c3 = cmulf(c3, ub4);
            { const float2 Zn = shx2(z[R - g], 63); PAIRE(g, z[g], Zn, c0.x, c0.y) }
            if (g + 1 <= R2_) { const float2 Zn = shx2(z[R - g - 1], 63); PAIRE(g + 1, z[g + 1], Zn, c1.x, c1.y) }
            if (g + 2 <= R2_) { const float2 Zn = shx2(z[R - g - 2], 63); PAIRE(g + 2, z[g + 2], Zn, c2.x, c2.y) }
            if (g + 3 <= R2_) { const float2 Zn = shx2(z[R - g - 3], 63); PAIRE(g + 3, z[g + 3], Zn, c3.x, c3.y) }
        }
    }
#undef PAIRE
#undef SWZK

    // coalesced transpose-out: raw (still-swizzled) rows -> global A rows
    if (valid) {
        const uint4* src = powsU + sub * (KPAD / 8);
        uint4* dst = (uint4*)(pows_g + (size_t)((size_t)b * n0 + t) * KPAD);
        #pragma unroll
        for (int w = 0; w < (NOCT + 63) / 64; ++w) {
            const int oct = p + 64 * w;
            if (oct < NOCT) dst[oct] = src[oct];
        }
    }
}

// ============ mel convert body (bakes the involution into melT) ============
template<int KPAD, int LOGR, int R, int K>
__device__ __forceinline__ void melcvt_one(const float* __restrict__ mel,
                                           unsigned short* __restrict__ melT, int idx) {
    const int n = idx / KPAD, pos = idx - n * KPAD;
    const int k = (pos & ~(R - 1)) | ((pos & (R - 1)) ^ ((pos >> LOGR) & (R - 1)));
    unsigned short v = 0;
    if (k < K) {
        const unsigned u = __float_as_uint(mel[(size_t)k * NMEL + n]);
        v = (unsigned short)((u + 0x7FFF + ((u >> 16) & 1)) >> 16);   // RNE
    }
    melT[(size_t)n * KPAD + pos] = v;
}

// ============ mel GEMM body via MFMA (R12-best): 4 independent waves,
// each owns a 16-frame tile with acc[5] ILP, full K, no LDS, no barrier ============
template<int KPAD, int SZI>
__device__ __forceinline__ void gemm_body(const unsigned short* __restrict__ powsA,
                                          const unsigned short* __restrict__ melT,
                                          float* __restrict__ out, int Mvalid, int gbid) {
    constexpr int NCH = KPAD / 32;

    const int tid = threadIdx.x;
    const int w   = tid >> 6;
    const int l   = tid & 63;
    const int frame0 = gbid * 64 + w * 16;

    const unsigned short* Ap = powsA + (size_t)(frame0 + (l & 15)) * KPAD + (l >> 4) * 8;
    const unsigned short* Bp = melT + (size_t)(l & 15) * KPAD + (l >> 4) * 8;

    f32x4 acc[5];
    const f32x4 z4 = {0.0f, 0.0f, 0.0f, 0.0f};
    #pragma unroll
    for (int nt = 0; nt < 5; ++nt) acc[nt] = z4;

    #pragma unroll 2
    for (int c = 0; c < NCH; ++c) {
        const bf16x8 a = *(const bf16x8*)(Ap + c * 32);
        #pragma unroll
        for (int nt = 0; nt < 5; ++nt) {
            const bf16x8 bb = *(const bf16x8*)(Bp + (size_t)nt * 16 * KPAD + c * 32);
            acc[nt] = __builtin_amdgcn_mfma_f32_16x16x32_bf16(a, bb, acc[nt], 0, 0, 0);
        }
    }

    #pragma unroll
    for (int nt = 0; nt < 5; ++nt) {
        #pragma unroll
        for (int q = 0; q < 4; ++q) {
            const int row = (l >> 4) * 4 + q;
            const int col = nt * 16 + (l & 15);
            const int frame = frame0 + row;
            if (frame < Mvalid)
                out[((size_t)frame * NMEL + col) * 3 + SZI] = logf(acc[nt][q] + 1e-16f);
        }
    }
}

// ================== K1: all three FFTs + mel-convert, one launch ==================
__global__ __launch_bounds__(256, 4)
void k_ffts(const float* __restrict__ x,
            const float* __restrict__ w1, const float* __restrict__ w2, const float* __restrict__ w4,
            const float* __restrict__ m1, const float* __restrict__ m2, const float* __restrict__ m4,
            unsigned short* __restrict__ p1, unsigned short* __restrict__ p2, unsigned short* __restrict__ p4,
            unsigned short* __restrict__ m1t, unsigned short* __restrict__ m2t, unsigned short* __restrict__ m4t,
            int T, int n0, int gx) {
    __shared__ uint4 sh[4 * 2080 / 8];              // max branch LDS (16640 B)
    int bid = blockIdx.x;
    const int nf = gx * 8;
    if (bid < nf) { fft_body<4096, 2080>(x, w4, p4, T, n0, bid % gx, bid / gx, sh); return; }
    bid -= nf;
    if (bid < nf) { fft_body<2048, 1056>(x, w2, p2, T, n0, bid % gx, bid / gx, sh); return; }
    bid -= nf;
    if (bid < nf) { fft_body<1024,  544>(x, w1, p1, T, n0, bid % gx, bid / gx, sh); return; }
    bid -= nf;
    int idx = bid * 256 + (int)threadIdx.x;
    constexpr int S1 = NMEL * 544, S2 = NMEL * 1056, S4 = NMEL * 2080;
    if (idx < S1) { melcvt_one< 544, 3,  8,  513>(m1, m1t, idx); return; }
    idx -= S1;
    if (idx < S2) { melcvt_one<1056, 4, 16, 1025>(m2, m2t, idx); return; }
    idx -= S2;
    if (idx < S4) melcvt_one<2080, 5, 32, 2049>(m4, m4t, idx);
}

// ================== K2: all three mel GEMMs, one launch ==================
__global__ __launch_bounds__(256)
void k_gemms(const unsigned short* __restrict__ p1, const unsigned short* __restrict__ p2,
             const unsigned short* __restrict__ p4,
             const unsigned short* __restrict__ m1t, const unsigned short* __restrict__ m2t,
             const unsigned short* __restrict__ m4t,
             float* __restrict__ out, int Mvalid, int ngemm) {
    int bid = blockIdx.x;
    if (bid < ngemm) { gemm_body<2080, 2>(p4, m4t, out, Mvalid, bid); return; }
    bid -= ngemm;
    if (bid < ngemm) { gemm_body<1056, 1>(p2, m2t, out, Mvalid, bid); return; }
    bid -= ngemm;
    gemm_body< 544, 0>(p1, m1t, out, Mvalid, bid);
}

// ================== FALLBACK (exact R7 kernel, known-passing) ==================
template<int FLEN, int SZI>
__global__ __launch_bounds__(512, 4)
void spect_kernel(const float* __restrict__ x, const float* __restrict__ win,
                  const float* __restrict__ mel, float* __restrict__ out,
                  int T, int n0) {
    constexpr int N    = FLEN / 2;
    constexpr int R    = N / 64;
    constexpr int LOGR = (R == 32) ? 5 : ((R == 16) ? 4 : 3);
    constexpr int R2_  = R / 2;
    constexpr int K    = N + 1;
    constexpr int KP   = N + 8;
    constexpr int HALF = FLEN / 2;
    constexpr int NT   = 512;
    constexpr int FPB  = 8;
    constexpr float PI = 3.14159265358979f;

    __shared__ uint4 pows4[KP];
    __shared__ float res[FPB * NMEL];
    unsigned short* pows = (unsigned short*)pows4;

    const int tid = threadIdx.x;
    const int sub = tid >> 6;
    const int p   = tid & 63;
    const int s   = brev6f(p);
    const int b   = blockIdx.y;
    const int t0  = blockIdx.x * FPB;

    for (int i = tid; i < FPB * NMEL; i += NT) res[i] = 0.0f;

    float2 W32s, W16s, W8s, W4s, W2s, wl, Pp, ub;
    float sg32, sg16, sg8, sg4, sg2, sg1;
    {
        float s_, c_;
        __sincosf(-PI * (float)(p & 31) / 32.0f, &s_, &c_);
        W32s = (p & 32) ? make_float2(c_, s_) : make_float2(1.0f, 0.0f);
        sg32 = (p & 32) ? -1.0f : 1.0f;
        __sincosf(-PI * (float)(p & 15) / 16.0f, &s_, &c_);
        W16s = (p & 16) ? make_float2(c_, s_) : make_float2(1.0f, 0.0f);
        sg16 = (p & 16) ? -1.0f : 1.0f;
        __sincosf(-PI * (float)(p & 7) / 8.0f, &s_, &c_);
        W8s  = (p & 8) ? make_float2(c_, s_) : make_float2(1.0f, 0.0f);
        sg8  = (p & 8) ? -1.0f : 1.0f;
        __sincosf(-PI * (float)(p & 3) / 4.0f, &s_, &c_);
        W4s  = (p & 4) ? make_float2(c_, s_) : make_float2(1.0f, 0.0f);
        sg4  = (p & 4) ? -1.0f : 1.0f;
        __sincosf(-PI * (float)(p & 1) / 2.0f, &s_, &c_);
        W2s  = (p & 2) ? make_float2(c_, s_) : make_float2(1.0f, 0.0f);
        sg2  = (p & 2) ? -1.0f : 1.0f;
        sg1  = (p & 1) ? -1.0f : 1.0f;
        __sincosf(-2.0f * PI * (float)p / (float)N, &s_, &c_); wl = make_float2(c_, s_);
        __sincosf(PI * (float)s / 64.0f, &s_, &c_);             Pp = make_float2(c_, s_);
        __sincosf(PI / (float)N, &s_, &c_);                     ub = make_float2(c_, s_);
    }
    const int mpart = brev6f((64 - s) & 63);

    const float* xb = x + (size_t)b * (size_t)T;
    const int Tp = T + HALF;

    const int t = t0 + sub;
    const bool valid = (t < n0);
    const int start = HOP * t;
    int pad = start + FLEN - Tp; if (pad < 0) pad = 0;
    const int base = start - pad - HALF;

    float2 z[R];
    if (pad == 0 && base >= 0 && valid) {
        const float*  xp = xb + base + 2 * p;
        const float2* wp = ((const float2*)win) + p;
        #pragma unroll
        for (int j = 0; j < R; ++j) {
            const int q = brevn(j, LOGR);
            const float2 wv = wp[64 * q];
            z[j] = make_float2(xp[128 * q] * wv.x, xp[128 * q + 1] * wv.y);
        }
    } else {
        #pragma unroll
        for (int j = 0; j < R; ++j) {
            const int q  = brevn(j, LOGR);
            const int i  = 64 * q + p;
            const int j0 = 2 * i;
            const float2 wv = ((const float2*)win)[i];
            const int xi0 = base + j0;
            float v0 = (valid && j0 >= pad     && xi0 >= 0)     ? xb[xi0] * wv.x     : 0.0f;
            float v1 = (valid && j0 + 1 >= pad && xi0 + 1 >= 0) ? xb[xi0 + 1] * wv.y : 0.0f;
            z[j] = make_float2(v0, v1);
        }
    }

    #pragma unroll
    for (int h = 1; h < R; h <<= 1) {
        #pragma unroll
        for (int base2 = 0; base2 < R; base2 += 2 * h) {
            #pragma unroll
            for (int i = 0; i < h; ++i) {
                const float2 W  = w32t((16 * i) / h);
                const float2 tt = cmulf(W, z[base2 + i + h]);
                const float2 aa = z[base2 + i];
                z[base2 + i]     = cadd(aa, tt);
                z[base2 + i + h] = csub(aa, tt);
            }
        }
    }

    {
        const float2 w2c = cmulf(wl, wl);
        const float2 w3c = cmulf(w2c, wl);
        const float2 w4c = cmulf(w2c, w2c);
        z[1] = cmulf(z[1], wl);
        z[2] = cmulf(z[2], w2c);
        z[3] = cmulf(z[3], w3c);
        float2 a0 = w4c, a1 = cmulf(wl, w4c), a2 = cmulf(w2c, w4c), a3 = cmulf(w3c, w4c);
        #pragma unroll
        for (int g = 4; g < R; g += 4) {
            z[g]     = cmulf(z[g],     a0);
            z[g + 1] = cmulf(z[g + 1], a1);
            z[g + 2] = cmulf(z[g + 2], a2);
            z[g + 3] = cmulf(z[g + 3], a3);
            if (g + 4 < R) {
                a0 = cmulf(a0, w4c); a1 = cmulf(a1, w4c);
                a2 = cmulf(a2, w4c); a3 = cmulf(a3, w4c);
            }
        }
    }

#define XSTAGE(MASK, W, SG) { \
        _Pragma("unroll") \
        for (int j = 0; j < R; ++j) { \
            const float2 xq = shx2(z[j], MASK); \
            const float2 d  = make_float2(fmaf(SG, z[j].x, xq.x), \
                                          fmaf(SG, z[j].y, xq.y)); \
            z[j] = cmulf(d, W); \
        } }
    XSTAGE(32, W32s, sg32)
    XSTAGE(16, W16s, sg16)
    XSTAGE(8,  W8s,  sg8)
    XSTAGE(4,  W4s,  sg4)
    XSTAGE(2,  W2s,  sg2)
    #pragma unroll
    for (int j = 0; j < R; ++j) {
        const float2 xq = shx2(z[j], 1);
        z[j] = make_float2(fmaf(sg1, z[j].x, xq.x), fmaf(sg1, z[j].y, xq.y));
    }
#undef XSTAGE

#define PAIRE(RR, ZK, ZN, CW, SW) { \
        const float Er = 0.5f * ((ZK).x + (ZN).x), Ei = 0.5f * ((ZK).y - (ZN).y); \
        const float Or = 0.5f * ((ZK).y + (ZN).y), Oi = -0.5f * ((ZK).x - (ZN).x); \
        const float Tr = (CW) * Or + (SW) * Oi; \
        const float Ti = (CW) * Oi - (SW) * Or; \
        const float Xr0 = Er + Tr, Xi0 = Ei + Ti; \
        const float Xr1 = Er - Tr, Xi1 = Ei - Ti; \
        const float pw0 = Xr0 * Xr0 + Xi0 * Xi0; \
        const float pw1 = Xr1 * Xr1 + Xi1 * Xi1; \
        const int k0b  = R * s + (RR); \
        const int km   = N - k0b; \
        const int row0 = (k0b & ~(R - 1)) | ((k0b & (R - 1)) ^ (s & 7)); \
        const int row1 = (km  & ~(R - 1)) | ((km  & (R - 1)) ^ ((km >> LOGR) & 7)); \
        pows[row0 * 8 + sub] = bf16t(pw0); \
        pows[row1 * 8 + sub] = bf16t(pw1); }

    {
        const float2 ub2 = cmulf(ub, ub);
        const float2 ub4 = cmulf(ub2, ub2);
        float2 c0 = Pp, c1 = cmulf(Pp, ub), c2 = cmulf(Pp, ub2), c3 = cmulf(c1, ub2);
        {
            const float2 Zn = shidx2(z[0], mpart);
            PAIRE(0, z[0], Zn, c0.x, c0.y)
        }
        { const float2 Zn = shx2(z[R - 1], 63); PAIRE(1, z[1], Zn, c1.x, c1.y) }
        { const float2 Zn = shx2(z[R - 2], 63); PAIRE(2, z[2], Zn, c2.x, c2.y) }
        { const float2 Zn = shx2(z[R - 3], 63); PAIRE(3, z[3], Zn, c3.x, c3.y) }
        #pragma unroll
        for (int g = 4; g <= R2_; g += 4) {
            c0 = cmulf(c0, ub4); c1 = cmulf(c1, ub4);
            c2 = cmulf(c2, ub4); c3 = cmulf(c3, ub4);
            { const float2 Zn = shx2(z[R - g], 63); PAIRE(g, z[g], Zn, c0.x, c0.y) }
            if (g + 1 <= R2_) { const float2 Zn = shx2(z[R - g - 1], 63); PAIRE(g + 1, z[g + 1], Zn, c1.x, c1.y) }
            if (g + 2 <= R2_) { const float2 Zn = shx2(z[R - g - 2], 63); PAIRE(g + 2, z[g + 2], Zn, c2.x, c2.y) }
            if (g + 3 <= R2_) { const float2 Zn = shx2(z[R - g - 3], 63); PAIRE(g + 3, z[g + 3], Zn, c3.x, c3.y) }
        }
    }
#undef PAIRE

    __syncthreads();

    constexpr int NCH = 25;
    constexpr int CH  = (K + NCH - 1) / NCH;
    if (tid < NCH * 20) {
        const int g  = tid % 20;
        const int cc = tid / 20;
        const int k0 = cc * CH;
        const int k1 = (k0 + CH < K) ? (k0 + CH) : K;
        float acc[FPB][4];
        #pragma unroll
        for (int f2 = 0; f2 < FPB; ++f2) {
            acc[f2][0] = 0.f; acc[f2][1] = 0.f; acc[f2][2] = 0.f; acc[f2][3] = 0.f;
        }
        #pragma unroll 4
        for (int k = k0; k < k1; ++k) {
            const int kmel = (k & ~(R - 1)) | ((k & (R - 1)) ^ ((k >> LOGR) & 7));
            const float4 mr = *(const float4*)(mel + (size_t)kmel * NMEL + 4 * g);
            const uint4 pv = pows4[k];
#define ACC2(W32, BASE) { \
            const float p0 = __uint_as_float((W32) << 16); \
            const float p1 = __uint_as_float((W32) & 0xFFFF0000u); \
            acc[BASE][0] += p0 * mr.x; acc[BASE][1] += p0 * mr.y; \
            acc[BASE][2] += p0 * mr.z; acc[BASE][3] += p0 * mr.w; \
            acc[(BASE)+1][0] += p1 * mr.x; acc[(BASE)+1][1] += p1 * mr.y; \
            acc[(BASE)+1][2] += p1 * mr.z; acc[(BASE)+1][3] += p1 * mr.w; }
            ACC2(pv.x, 0) ACC2(pv.y, 2) ACC2(pv.z, 4) ACC2(pv.w, 6)
#undef ACC2
        }
        #pragma unroll
        for (int f2 = 0; f2 < FPB; ++f2) {
            #pragma unroll
            for (int mi = 0; mi < 4; ++mi) {
                atomicAdd(&res[f2 * NMEL + 4 * g + mi], acc[f2][mi]);
            }
        }
    }
    __syncthreads();

    const size_t outbase = (size_t)b * (size_t)n0 * NMEL * 3;
    for (int i = tid; i < FPB * NMEL; i += NT) {
        const int f2 = i / NMEL;
        const int m  = i % NMEL;
        const int tt = t0 + f2;
        if (tt < n0) {
            out[outbase + ((size_t)tt * NMEL + m) * 3 + SZI] = logf(res[i] + 1e-16f);
        }
    }
}

extern "C" void kernel_launch(void* const* d_in, const int* in_sizes, int n_in,
                              void* d_out, int out_size, void* d_ws, size_t ws_size,
                              hipStream_t stream) {
    const float* x  = (const float*)d_in[0];
    const float* w1 = (const float*)d_in[1];
    const float* m1 = (const float*)d_in[2];
    const float* w2 = (const float*)d_in[3];
    const float* m2 = (const float*)d_in[4];
    const float* w4 = (const float*)d_in[5];
    const float* m4 = (const float*)d_in[6];
    float* out = (float*)d_out;

    const int B  = 8;
    const int T  = in_sizes[0] / B;
    const int n0 = (T + 512 + 440) / 441;   // ceil((T + 1024/2) / 441)

    const size_t M    = (size_t)B * (size_t)n0;
    const size_t Mpad = (M + 63) & ~(size_t)63;          // 64-frame GEMM tiles
    const size_t KP1 = 544, KP2 = 1056, KP4 = 2080;
    const size_t need = (Mpad + NMEL) * (KP1 + KP2 + KP4) * 2;

    if (ws_size >= need) {
        unsigned short* p1  = (unsigned short*)d_ws;
        unsigned short* p2  = p1 + Mpad * KP1;
        unsigned short* p4  = p2 + Mpad * KP2;
        unsigned short* m1t = p4 + Mpad * KP4;
        unsigned short* m2t = m1t + NMEL * KP1;
        unsigned short* m4t = m2t + NMEL * KP2;

        const int gx  = (n0 + 3) / 4;
        const int nf  = gx * 8;
        const int cvt = (NMEL * (544 + 1056 + 2080) + 255) / 256;
        const int ngemm = (int)(Mpad / 64);

        k_ffts<<<3 * nf + cvt, 256, 0, stream>>>(x, w1, w2, w4, m1, m2, m4,
                                                 p1, p2, p4, m1t, m2t, m4t, T, n0, gx);
        k_gemms<<<3 * ngemm, 256, 0, stream>>>(p1, p2, p4, m1t, m2t, m4t,
                                               out, (int)M, ngemm);
    } else {
        const int gxf = (n0 + 7) / 8;
        spect_kernel<1024, 0><<<dim3(gxf, B), 512, 0, stream>>>(x, w1, m1, out, T, n0);
        spect_kernel<2048, 1><<<dim3(gxf, B), 512, 0, stream>>>(x, w2, m2, out, T, n0);
        spect_kernel<4096, 2><<<dim3(gxf, B), 512, 0, stream>>>(x, w4, m4, out, T, n0);
    }
}